// Round 1
// baseline (254.667 us; speedup 1.0000x reference)
//
#include <hip/hip_runtime.h>

#define D 64
#define PACK 256  // packed floats per node: BATCH * D

typedef __attribute__((ext_vector_type(8))) short bf16x8;
typedef __attribute__((ext_vector_type(4))) float f32x4;
typedef __attribute__((ext_vector_type(8))) unsigned short ushort8;

__device__ __forceinline__ unsigned short f2bf(float f) {
  unsigned int u = __float_as_uint(f);
  u += 0x7FFFu + ((u >> 16) & 1u);  // RNE (inputs finite)
  return (unsigned short)(u >> 16);
}
__device__ __forceinline__ float bf2f(unsigned short h) {
  union { unsigned int u; float f; } v;
  v.u = ((unsigned int)h) << 16;
  return v.f;
}

// --- Phase 1 (fused): xwb = bf16(x @ W) via MFMA + row-degree histogram.
// Wave = 16-node M-tile, full N=64. A-frags from global (4 float4/lane),
// B(W) in 32 VGPRs. 8 mfma_f32_16x16x32_bf16 per tile. No LDS.
__global__ __launch_bounds__(256) void gemm_hist_kernel(
    const float* __restrict__ x, const float* __restrict__ W,
    unsigned short* __restrict__ xwb, const int* __restrict__ rows,
    int* __restrict__ cnt, int total_nodes, int N, int E) {
  const int tid  = threadIdx.x;
  const int lane = tid & 63;
  const int c = lane & 15;  // m (A) / n (B) / col (D) within 16-tile
  const int q = lane >> 4;  // quad: k-octet (A,B) / row-group (D)

  // B-operand frags: B[k][n] = W[k*64+n]; n = nt*16+c, k = h*32 + q*8 + j.
  bf16x8 Bf[4][2];
#pragma unroll
  for (int nt = 0; nt < 4; ++nt) {
#pragma unroll
    for (int h = 0; h < 2; ++h) {
      const int n  = nt * 16 + c;
      const int k0 = h * 32 + q * 8;
#pragma unroll
      for (int j = 0; j < 8; ++j)
        Bf[nt][h][j] = (short)f2bf(W[(k0 + j) * D + n]);
    }
  }

  const float4* __restrict__ x4 = (const float4*)x;
  const int ntiles = (total_nodes + 15) >> 4;
  const int wave_g = blockIdx.x * 4 + (tid >> 6);
  const int nwaves = gridDim.x * 4;

  for (int tile = wave_g; tile < ntiles; tile += nwaves) {
    const int base = tile * 16;
    const int node = min(base + c, total_nodes - 1);
    const float4* xr = x4 + (size_t)node * 16;
    const float4 p0 = xr[q * 2 + 0];
    const float4 p1 = xr[q * 2 + 1];
    const float4 p2 = xr[8 + q * 2 + 0];
    const float4 p3 = xr[8 + q * 2 + 1];
    bf16x8 a0, a1;
    a0[0] = (short)f2bf(p0.x); a0[1] = (short)f2bf(p0.y);
    a0[2] = (short)f2bf(p0.z); a0[3] = (short)f2bf(p0.w);
    a0[4] = (short)f2bf(p1.x); a0[5] = (short)f2bf(p1.y);
    a0[6] = (short)f2bf(p1.z); a0[7] = (short)f2bf(p1.w);
    a1[0] = (short)f2bf(p2.x); a1[1] = (short)f2bf(p2.y);
    a1[2] = (short)f2bf(p2.z); a1[3] = (short)f2bf(p2.w);
    a1[4] = (short)f2bf(p3.x); a1[5] = (short)f2bf(p3.y);
    a1[6] = (short)f2bf(p3.z); a1[7] = (short)f2bf(p3.w);

    f32x4 acc[4];
#pragma unroll
    for (int nt = 0; nt < 4; ++nt) {
      f32x4 z = {0.f, 0.f, 0.f, 0.f};
      z = __builtin_amdgcn_mfma_f32_16x16x32_bf16(a0, Bf[nt][0], z, 0, 0, 0);
      z = __builtin_amdgcn_mfma_f32_16x16x32_bf16(a1, Bf[nt][1], z, 0, 0, 0);
      acc[nt] = z;
    }
    // D: node m = q*4 + r, ch = nt*16 + c.
#pragma unroll
    for (int r = 0; r < 4; ++r) {
      const int fn = base + q * 4 + r;
      if (fn >= total_nodes) break;
      const int b  = (fn >= N) + (fn >= 2 * N) + (fn >= 3 * N);
      const int nn = fn - b * N;
      unsigned short* dst = xwb + (size_t)nn * PACK + b * D + c;
#pragma unroll
      for (int nt = 0; nt < 4; ++nt) dst[nt * 16] = f2bf(acc[nt][r]);
    }
  }

  // Fused row-degree histogram; cnt pre-zeroed by the memset.
  const int gtid = blockIdx.x * 256 + tid;
  const int gstr = gridDim.x * 256;
  for (int e = gtid; e < E; e += gstr) atomicAdd(&cnt[rows[e]], 1);
}

// --- Sort step 2a: per-block exclusive scan + block totals ---
__global__ __launch_bounds__(1024) void scan_a_kernel(
    const int* __restrict__ cnt, int* __restrict__ start,
    int* __restrict__ partial, int n) {
  __shared__ int s[1024];
  const int t = threadIdx.x;
  const int i = blockIdx.x * 1024 + t;
  const int v = (i < n) ? cnt[i] : 0;
  s[t] = v;
  __syncthreads();
  for (int off = 1; off < 1024; off <<= 1) {
    const int u = (t >= off) ? s[t - off] : 0;
    __syncthreads();
    s[t] += u;
    __syncthreads();
  }
  if (i < n) start[i] = s[t] - v;
  if (t == 1023) partial[blockIdx.x] = s[1023];
}

// --- Sort step 2bc: apply block offsets, init cursor, start[n]=E ---
__global__ __launch_bounds__(1024) void scan_bc_kernel(
    const int* __restrict__ partial, int* __restrict__ start,
    int* __restrict__ cursor, int n, int E) {
  __shared__ int soff;
  if (threadIdx.x < 64) {
    int v = 0;
    for (int j = threadIdx.x; j < (int)blockIdx.x; j += 64) v += partial[j];
#pragma unroll
    for (int d = 32; d > 0; d >>= 1) v += __shfl_down(v, d);
    if (threadIdx.x == 0) soff = v;
  }
  __syncthreads();
  const int i = blockIdx.x * 1024 + threadIdx.x;
  if (i < n) {
    const int sv = start[i] + soff;
    start[i] = sv;
    cursor[i] = sv;
  }
  if (blockIdx.x == 0 && threadIdx.x == 0) start[n] = E;
}

// --- Sort step 3: drop {col,a} into row segments ---
__global__ __launch_bounds__(256) void permute_kernel(
    const int* __restrict__ rows, const int* __restrict__ cols,
    const float* __restrict__ a_vals, int* __restrict__ cursor,
    int2* __restrict__ meta, int E) {
  const int e = blockIdx.x * blockDim.x + threadIdx.x;
  if (e >= E) return;
  const int pos = atomicAdd(&cursor[rows[e]], 1);
  meta[pos] = make_int2(cols[e], __float_as_int(a_vals[e]));
}

// --- Phase 2: gather-reduce. One wave per row, grid-stride (2048 blocks
// stay resident -> steady 8 blocks/CU). Each load instruction carries TWO
// edges: half-wave h = lane>>5 handles edge 2i+h, lane c = lane&31 owns 8
// contiguous channels (ushort8 = 16B dwordx4 per lane, 512B per half-wave).
// Meta loaded 64-edges-at-a-time coalesced; cols/weights broadcast via
// readlane; 8 load-instructions (16 edges) in flight per group. Final
// cross-half combine via one shfl_xor(32) per accumulator. ---
__global__ __launch_bounds__(256) void gather_kernel(
    const unsigned short* __restrict__ xwb, const int* __restrict__ start,
    const int2* __restrict__ meta, float* __restrict__ out,
    int N, int stride_b) {
  const int lane = threadIdx.x & 63;
  const int h = lane >> 5;   // which edge of the pair
  const int c = lane & 31;   // 8-channel group within the 256-float row
  const int wid = blockIdx.x * 4 + (threadIdx.x >> 6);
  const int nw = gridDim.x * 4;
  const ushort8* __restrict__ xw8 = (const ushort8*)xwb;

  for (int r = wid; r < N; r += nw) {
    int j0 = start[r];
    const int je = start[r + 1];

    float acc[8] = {0.f, 0.f, 0.f, 0.f, 0.f, 0.f, 0.f, 0.f};
    while (j0 < je) {
      const int cnt = min(64, je - j0);
      const int2 mv = meta[j0 + min(lane, cnt - 1)];  // coalesced 8B/lane
#pragma unroll
      for (int k = 0; k < 64; k += 16) {
        if (k >= cnt) break;
        ushort8 uu[8];
        float aa[8];
#pragma unroll
        for (int i = 0; i < 8; ++i) {
          const int s0 = k + 2 * i;
          const int c0 = __builtin_amdgcn_readlane(mv.x, s0);
          const int c1 = __builtin_amdgcn_readlane(mv.x, s0 + 1);
          const int a0 = __builtin_amdgcn_readlane(mv.y, s0);
          const int a1 = __builtin_amdgcn_readlane(mv.y, s0 + 1);
          const int cc = h ? c1 : c0;
          const float av = __int_as_float(h ? a1 : a0);
          // padded slots: valid (clamped) col -> dup address (L1 hit), zero w
          aa[i] = (s0 + h < cnt) ? av : 0.f;
          uu[i] = xw8[(size_t)cc * 32 + c];  // 16B/lane, 2 edges per instr
        }
#pragma unroll
        for (int i = 0; i < 8; ++i) {
#pragma unroll
          for (int j = 0; j < 8; ++j)
            acc[j] = fmaf(aa[i], bf2f(uu[i][j]), acc[j]);
        }
      }
      j0 += 64;
    }

    // combine the two half-wave partial sums (lanes l and l^32 hold the
    // same 8 channels over disjoint edge subsets)
#pragma unroll
    for (int j = 0; j < 8; ++j) acc[j] += __shfl_xor(acc[j], 32);

    // lane (h,c) writes channels c*8 + h*4 .. +3 of the packed 256
    const int i0 = c * 8 + h * 4;
    const int b  = i0 >> 6;
    const int ch = i0 & 63;
    float4 o;
    o.x = acc[h * 4 + 0]; o.y = acc[h * 4 + 1];
    o.z = acc[h * 4 + 2]; o.w = acc[h * 4 + 3];
    *(float4*)(out + (size_t)b * stride_b + (size_t)r * D + ch) = o;
  }
}

extern "C" void kernel_launch(void* const* d_in, const int* in_sizes, int n_in,
                              void* d_out, int out_size, void* d_ws,
                              size_t ws_size, hipStream_t stream) {
  const float* x      = (const float*)d_in[0];
  const float* W      = (const float*)d_in[1];
  const int*   rows   = (const int*)d_in[2];
  const int*   cols   = (const int*)d_in[3];
  const float* a_vals = (const float*)d_in[4];

  const int E           = in_sizes[2];
  const int total_nodes = in_sizes[0] / D;  // B*N
  const int N           = total_nodes / 4;
  const int stride_b    = N * D;

  // Workspace layout (16B-aligned slabs)
  char* ws = (char*)d_ws;
  unsigned short* xwb = (unsigned short*)ws;  ws += (size_t)N * PACK * sizeof(unsigned short);
  int2* meta   = (int2*)ws;                   ws += (size_t)E * sizeof(int2);
  int* start   = (int*)ws;                    ws += (size_t)(N + 4) * sizeof(int);
  int* cursor  = (int*)ws;                    ws += (size_t)N * sizeof(int);
  int* partial = (int*)ws;

  hipMemsetAsync(cursor, 0, (size_t)N * sizeof(int), stream);

  gemm_hist_kernel<<<2048, 256, 0, stream>>>(x, W, xwb, rows, cursor,
                                             total_nodes, N, E);

  const int sb = (N + 1023) / 1024;
  scan_a_kernel<<<sb, 1024, 0, stream>>>(cursor, start, partial, N);
  scan_bc_kernel<<<sb, 1024, 0, stream>>>(partial, start, cursor, N, E);

  const int eb = (E + 255) / 256;
  permute_kernel<<<eb, 256, 0, stream>>>(rows, cols, a_vals, cursor, meta, E);

  gather_kernel<<<2048, 256, 0, stream>>>(xwb, start, meta, (float*)d_out, N,
                                          stride_b);
}